// Round 1
// baseline (5122.042 us; speedup 1.0000x reference)
//
#include <hip/hip_runtime.h>
#include <hip/hip_bf16.h>

#define D 64
#define D4 16  // float4s per row

// ---------------------------------------------------------------------------
// concat user_emb + item_emb into buf (N_TOTAL x D), float4-vectorized
__global__ void concat_init_kernel(const float* __restrict__ user_emb,
                                   const float* __restrict__ item_emb,
                                   float* __restrict__ buf,
                                   int n_user_rows, int n_total_rows) {
    size_t t = (size_t)blockIdx.x * blockDim.x + threadIdx.x;
    size_t total4 = (size_t)n_total_rows * D4;
    size_t user4 = (size_t)n_user_rows * D4;
    for (size_t i = t; i < total4; i += (size_t)gridDim.x * blockDim.x) {
        float4 v;
        if (i < user4) v = reinterpret_cast<const float4*>(user_emb)[i];
        else           v = reinterpret_cast<const float4*>(item_emb)[i - user4];
        reinterpret_cast<float4*>(buf)[i] = v;
    }
}

// ---------------------------------------------------------------------------
// one propagation layer: dst[row[e]] += val[e] * src[col[e]]  (dst pre-zeroed)
// 16 threads per edge, float4 per thread, 4 scalar f32 atomics
__global__ void spmm_scatter_kernel(const int* __restrict__ row,
                                    const int* __restrict__ col,
                                    const float* __restrict__ val,
                                    const float* __restrict__ src,
                                    float* __restrict__ dst,
                                    int n_edges) {
    int t = blockIdx.x * blockDim.x + threadIdx.x;
    int e = t >> 4;
    int lane = t & 15;
    if (e >= n_edges) return;
    int c = col[e];
    int r = row[e];
    float w = val[e];
    float4 m = reinterpret_cast<const float4*>(src + (size_t)c * D)[lane];
    float* d = dst + (size_t)r * D + lane * 4;
    atomicAdd(d + 0, w * m.x);
    atomicAdd(d + 1, w * m.y);
    atomicAdd(d + 2, w * m.z);
    atomicAdd(d + 3, w * m.w);
}

// ---------------------------------------------------------------------------
// accumulate this layer's embedding at the batch rows: u_acc[b] += buf[users[b]],
// v_acc[b] += buf[n_user_rows + items[b]]
__global__ void gather_acc_kernel(const int* __restrict__ users,
                                  const int* __restrict__ items,
                                  const float* __restrict__ buf,
                                  float* __restrict__ u_acc,
                                  float* __restrict__ v_acc,
                                  int batch, int n_user_rows) {
    int t = blockIdx.x * blockDim.x + threadIdx.x;
    int b = t >> 4;
    int lane = t & 15;
    if (b >= batch) return;
    int ur = users[b];
    int vr = n_user_rows + items[b];
    float4 uu = reinterpret_cast<const float4*>(buf + (size_t)ur * D)[lane];
    float4 vv = reinterpret_cast<const float4*>(buf + (size_t)vr * D)[lane];
    float4* up = reinterpret_cast<float4*>(u_acc + (size_t)b * D) + lane;
    float4* vp = reinterpret_cast<float4*>(v_acc + (size_t)b * D) + lane;
    float4 a = *up, c = *vp;
    a.x += uu.x; a.y += uu.y; a.z += uu.z; a.w += uu.w;
    c.x += vv.x; c.y += vv.y; c.z += vv.z; c.w += vv.w;
    *up = a;
    *vp = c;
}

// ---------------------------------------------------------------------------
// gamma[b] = dot(u_acc[b], v_acc[b]) / 16 (mean over 4 layers on each side),
// loss = mean BCEWithLogits; atomicAdd block partials into out[0]
__global__ void loss_kernel(const float* __restrict__ u_acc,
                            const float* __restrict__ v_acc,
                            const float* __restrict__ labels,
                            float* __restrict__ out, int batch) {
    int b = blockIdx.x * blockDim.x + threadIdx.x;
    float lb = 0.0f;
    if (b < batch) {
        const float4* up = reinterpret_cast<const float4*>(u_acc + (size_t)b * D);
        const float4* vp = reinterpret_cast<const float4*>(v_acc + (size_t)b * D);
        float g = 0.0f;
#pragma unroll
        for (int i = 0; i < D4; ++i) {
            float4 a = up[i], c = vp[i];
            g += a.x * c.x + a.y * c.y + a.z * c.z + a.w * c.w;
        }
        g *= (1.0f / 16.0f);  // (sum/4) . (sum/4)
        float y = labels[b];
        lb = fmaxf(g, 0.0f) - g * y + log1pf(expf(-fabsf(g)));
    }
    // wave reduce (64 lanes)
    for (int off = 32; off > 0; off >>= 1)
        lb += __shfl_down(lb, off, 64);
    __shared__ float sdata[4];
    int lane = threadIdx.x & 63;
    int wid = threadIdx.x >> 6;
    if (lane == 0) sdata[wid] = lb;
    __syncthreads();
    if (threadIdx.x == 0) {
        float s = sdata[0] + sdata[1] + sdata[2] + sdata[3];
        atomicAdd(out, s / (float)batch);
    }
}

// ---------------------------------------------------------------------------
extern "C" void kernel_launch(void* const* d_in, const int* in_sizes, int n_in,
                              void* d_out, int out_size, void* d_ws, size_t ws_size,
                              hipStream_t stream) {
    const int* users = (const int*)d_in[0];
    const int* items = (const int*)d_in[1];
    const float* labels = (const float*)d_in[2];
    const int* edge_row = (const int*)d_in[3];
    const int* edge_col = (const int*)d_in[4];
    const float* edge_val = (const float*)d_in[5];
    const float* user_emb = (const float*)d_in[6];
    const float* item_emb = (const float*)d_in[7];

    const int batch = in_sizes[0];
    const int n_edges = in_sizes[3];
    const int n_user_rows = in_sizes[6] / D;   // 100001
    const int n_item_rows = in_sizes[7] / D;   // 50000
    const int n_total = n_user_rows + n_item_rows;

    const size_t table_bytes = (size_t)n_total * D * sizeof(float);  // 38.4 MB
    char* ws = (char*)d_ws;
    float* buf0 = (float*)(ws);
    float* buf1 = (float*)(ws + table_bytes);
    float* u_acc = (float*)(ws + 2 * table_bytes);
    float* v_acc = (float*)(ws + 2 * table_bytes + (size_t)batch * D * sizeof(float));

    const size_t acc_bytes = (size_t)batch * D * sizeof(float);

    // zero accumulators + output
    hipMemsetAsync(u_acc, 0, acc_bytes, stream);
    hipMemsetAsync(v_acc, 0, acc_bytes, stream);
    hipMemsetAsync(d_out, 0, sizeof(float) * out_size, stream);

    // layer 0: buf0 = concat
    {
        int threads = 256;
        int blocks = 2048;
        concat_init_kernel<<<blocks, threads, 0, stream>>>(user_emb, item_emb, buf0,
                                                           n_user_rows, n_total);
    }
    {
        int threads = 256;
        int blocks = (batch * 16 + 255) / 256;
        gather_acc_kernel<<<blocks, threads, 0, stream>>>(users, items, buf0,
                                                          u_acc, v_acc, batch, n_user_rows);
    }

    // 3 propagation layers, ping-ponging buf0 <-> buf1
    float* cur = buf0;
    float* nxt = buf1;
    const int spmm_threads = 256;
    const int spmm_blocks = (int)(((size_t)n_edges * 16 + spmm_threads - 1) / spmm_threads);
    const int ga_blocks = (batch * 16 + 255) / 256;
    for (int layer = 0; layer < 3; ++layer) {
        hipMemsetAsync(nxt, 0, table_bytes, stream);
        spmm_scatter_kernel<<<spmm_blocks, spmm_threads, 0, stream>>>(
            edge_row, edge_col, edge_val, cur, nxt, n_edges);
        gather_acc_kernel<<<ga_blocks, 256, 0, stream>>>(users, items, nxt,
                                                         u_acc, v_acc, batch, n_user_rows);
        float* tmp = cur; cur = nxt; nxt = tmp;
    }

    // final loss
    {
        int threads = 256;
        int blocks = (batch + threads - 1) / threads;
        loss_kernel<<<blocks, threads, 0, stream>>>(u_acc, v_acc, labels, (float*)d_out, batch);
    }
}

// Round 2
// 535.510 us; speedup vs baseline: 9.5648x; 9.5648x over previous
//
#include <hip/hip_runtime.h>
#include <hip/hip_bf16.h>

#define D 64
#define D4 16          // float4s per row
#define SCAN_CHUNK 2048

// ---------------------------------------------------------------------------
// concat user_emb + item_emb into buf (N_TOTAL x D), float4-vectorized
__global__ void concat_init_kernel(const float* __restrict__ user_emb,
                                   const float* __restrict__ item_emb,
                                   float* __restrict__ buf,
                                   int n_user_rows, int n_total_rows) {
    size_t t = (size_t)blockIdx.x * blockDim.x + threadIdx.x;
    size_t total4 = (size_t)n_total_rows * D4;
    size_t user4 = (size_t)n_user_rows * D4;
    for (size_t i = t; i < total4; i += (size_t)gridDim.x * blockDim.x) {
        float4 v;
        if (i < user4) v = reinterpret_cast<const float4*>(user_emb)[i];
        else           v = reinterpret_cast<const float4*>(item_emb)[i - user4];
        reinterpret_cast<float4*>(buf)[i] = v;
    }
}

// ---------------------------------------------------------------------------
// CSR build step 1: histogram of destination rows
__global__ void hist_kernel(const int* __restrict__ row, int* __restrict__ counts,
                            int n_edges) {
    int e = blockIdx.x * blockDim.x + threadIdx.x;
    if (e < n_edges) atomicAdd(&counts[row[e]], 1);
}

// CSR build step 2a: per-block exclusive scan (SCAN_CHUNK elems/block of 256 thr)
__global__ void scan_block_kernel(const int* __restrict__ counts,
                                  int* __restrict__ offsets,
                                  int* __restrict__ blocksums, int n) {
    __shared__ int lds[256];
    int base = blockIdx.x * SCAN_CHUNK;
    int tid = threadIdx.x;
    int local[8];
    int sum = 0;
#pragma unroll
    for (int j = 0; j < 8; ++j) {
        int idx = base + tid * 8 + j;
        int v = (idx < n) ? counts[idx] : 0;
        local[j] = sum;            // exclusive prefix within thread
        sum += v;
    }
    lds[tid] = sum;
    __syncthreads();
    // Hillis-Steele inclusive scan over 256 thread sums
    for (int off = 1; off < 256; off <<= 1) {
        int v = (tid >= off) ? lds[tid - off] : 0;
        __syncthreads();
        lds[tid] += v;
        __syncthreads();
    }
    int thread_prefix = (tid == 0) ? 0 : lds[tid - 1];
    if (tid == 255) blocksums[blockIdx.x] = lds[255];
#pragma unroll
    for (int j = 0; j < 8; ++j) {
        int idx = base + tid * 8 + j;
        if (idx < n) offsets[idx] = thread_prefix + local[j];
    }
}

// CSR build step 2b: serial exclusive scan of block sums (nblocks <= ~128)
__global__ void scan_sums_kernel(int* __restrict__ blocksums, int nblocks,
                                 int* __restrict__ offsets, int n) {
    if (threadIdx.x == 0 && blockIdx.x == 0) {
        int run = 0;
        for (int i = 0; i < nblocks; ++i) {
            int v = blocksums[i];
            blocksums[i] = run;
            run += v;
        }
        offsets[n] = run;  // total edge count
    }
}

// CSR build step 2c: add scanned block sums
__global__ void scan_add_kernel(int* __restrict__ offsets,
                                const int* __restrict__ blocksums, int n) {
    int idx = blockIdx.x * blockDim.x + threadIdx.x;
    int b = idx / SCAN_CHUNK;
    if (idx < n) offsets[idx] += blocksums[b];
}

// CSR build step 3: copy offsets -> cursor
__global__ void copy_kernel(const int* __restrict__ src, int* __restrict__ dst, int n) {
    int i = blockIdx.x * blockDim.x + threadIdx.x;
    if (i < n) dst[i] = src[i];
}

// CSR build step 4: scatter edges into row-sorted slots as (col, val) pairs
__global__ void fill_kernel(const int* __restrict__ row, const int* __restrict__ col,
                            const float* __restrict__ val, int* __restrict__ cursor,
                            int2* __restrict__ pairs, int n_edges) {
    int e = blockIdx.x * blockDim.x + threadIdx.x;
    if (e >= n_edges) return;
    int r = row[e];
    int pos = atomicAdd(&cursor[r], 1);
    pairs[pos] = make_int2(col[e], __float_as_int(val[e]));
}

// ---------------------------------------------------------------------------
// gather spmm: one wave per destination row; 4 lane-groups of 16 process 4
// edges in parallel, each group covers the full 64-float row as float4s.
// dst fully written (rows with no edges get zeros) -> no memset, no atomics.
__global__ void spmm_gather_kernel(const int* __restrict__ offsets,
                                   const int2* __restrict__ pairs,
                                   const float* __restrict__ src,
                                   float* __restrict__ dst, int n_total) {
    int wid = threadIdx.x >> 6;
    int lane = threadIdx.x & 63;
    int r = blockIdx.x * 4 + wid;
    if (r >= n_total) return;
    int start = offsets[r];
    int end = offsets[r + 1];
    int g = lane >> 4;       // edge slot within iteration
    int sub = lane & 15;     // float4 index within row
    float4 acc = make_float4(0.f, 0.f, 0.f, 0.f);
    const float4* src4 = reinterpret_cast<const float4*>(src);
    for (int k = start + g; k < end; k += 4) {
        int2 p = pairs[k];
        float w = __int_as_float(p.y);
        float4 m = src4[(size_t)p.x * D4 + sub];
        acc.x += w * m.x; acc.y += w * m.y; acc.z += w * m.z; acc.w += w * m.w;
    }
    // reduce the 4 lane-groups
    acc.x += __shfl_xor(acc.x, 16, 64);
    acc.y += __shfl_xor(acc.y, 16, 64);
    acc.z += __shfl_xor(acc.z, 16, 64);
    acc.w += __shfl_xor(acc.w, 16, 64);
    acc.x += __shfl_xor(acc.x, 32, 64);
    acc.y += __shfl_xor(acc.y, 32, 64);
    acc.z += __shfl_xor(acc.z, 32, 64);
    acc.w += __shfl_xor(acc.w, 32, 64);
    if (g == 0) reinterpret_cast<float4*>(dst)[(size_t)r * D4 + sub] = acc;
}

// ---------------------------------------------------------------------------
// accumulate this layer's embedding at the batch rows
__global__ void gather_acc_kernel(const int* __restrict__ users,
                                  const int* __restrict__ items,
                                  const float* __restrict__ buf,
                                  float* __restrict__ u_acc,
                                  float* __restrict__ v_acc,
                                  int batch, int n_user_rows) {
    int t = blockIdx.x * blockDim.x + threadIdx.x;
    int b = t >> 4;
    int lane = t & 15;
    if (b >= batch) return;
    int ur = users[b];
    int vr = n_user_rows + items[b];
    float4 uu = reinterpret_cast<const float4*>(buf + (size_t)ur * D)[lane];
    float4 vv = reinterpret_cast<const float4*>(buf + (size_t)vr * D)[lane];
    float4* up = reinterpret_cast<float4*>(u_acc + (size_t)b * D) + lane;
    float4* vp = reinterpret_cast<float4*>(v_acc + (size_t)b * D) + lane;
    float4 a = *up, c = *vp;
    a.x += uu.x; a.y += uu.y; a.z += uu.z; a.w += uu.w;
    c.x += vv.x; c.y += vv.y; c.z += vv.z; c.w += vv.w;
    *up = a;
    *vp = c;
}

// ---------------------------------------------------------------------------
// gamma[b] = dot(u_acc,v_acc)/16; loss = mean BCEWithLogits
__global__ void loss_kernel(const float* __restrict__ u_acc,
                            const float* __restrict__ v_acc,
                            const float* __restrict__ labels,
                            float* __restrict__ out, int batch) {
    int b = blockIdx.x * blockDim.x + threadIdx.x;
    float lb = 0.0f;
    if (b < batch) {
        const float4* up = reinterpret_cast<const float4*>(u_acc + (size_t)b * D);
        const float4* vp = reinterpret_cast<const float4*>(v_acc + (size_t)b * D);
        float g = 0.0f;
#pragma unroll
        for (int i = 0; i < D4; ++i) {
            float4 a = up[i], c = vp[i];
            g += a.x * c.x + a.y * c.y + a.z * c.z + a.w * c.w;
        }
        g *= (1.0f / 16.0f);
        float y = labels[b];
        lb = fmaxf(g, 0.0f) - g * y + log1pf(expf(-fabsf(g)));
    }
    for (int off = 32; off > 0; off >>= 1)
        lb += __shfl_down(lb, off, 64);
    __shared__ float sdata[4];
    int lane = threadIdx.x & 63;
    int wid = threadIdx.x >> 6;
    if (lane == 0) sdata[wid] = lb;
    __syncthreads();
    if (threadIdx.x == 0) {
        float s = sdata[0] + sdata[1] + sdata[2] + sdata[3];
        atomicAdd(out, s / (float)batch);
    }
}

// ---------------------------------------------------------------------------
extern "C" void kernel_launch(void* const* d_in, const int* in_sizes, int n_in,
                              void* d_out, int out_size, void* d_ws, size_t ws_size,
                              hipStream_t stream) {
    const int* users = (const int*)d_in[0];
    const int* items = (const int*)d_in[1];
    const float* labels = (const float*)d_in[2];
    const int* edge_row = (const int*)d_in[3];
    const int* edge_col = (const int*)d_in[4];
    const float* edge_val = (const float*)d_in[5];
    const float* user_emb = (const float*)d_in[6];
    const float* item_emb = (const float*)d_in[7];

    const int batch = in_sizes[0];
    const int n_edges = in_sizes[3];
    const int n_user_rows = in_sizes[6] / D;   // 100001
    const int n_item_rows = in_sizes[7] / D;   // 50000
    const int n_total = n_user_rows + n_item_rows;

    auto align256 = [](size_t x) { return (x + 255) & ~(size_t)255; };
    const size_t table_bytes = align256((size_t)n_total * D * sizeof(float));  // 38.4 MB
    const size_t acc_bytes = align256((size_t)batch * D * sizeof(float));      // 2 MB
    const size_t off_bytes = align256((size_t)(n_total + 1) * sizeof(int));    // 600 KB
    const size_t pairs_bytes = align256((size_t)n_edges * sizeof(int2));       // 16 MB

    char* ws = (char*)d_ws;
    float* buf0   = (float*)ws;                 ws += table_bytes;
    float* buf1   = (float*)ws;                 ws += table_bytes;
    float* u_acc  = (float*)ws;                 ws += acc_bytes;
    float* v_acc  = (float*)ws;                 ws += acc_bytes;
    int*   counts = (int*)ws;                   ws += off_bytes;
    int*   offsets= (int*)ws;                   ws += off_bytes;
    int*   cursor = (int*)ws;                   ws += off_bytes;
    int*   bsums  = (int*)ws;                   ws += 1024;
    int2*  pairs  = (int2*)ws;                  ws += pairs_bytes;

    // zero accumulators, histogram, output
    hipMemsetAsync(u_acc, 0, acc_bytes, stream);
    hipMemsetAsync(v_acc, 0, acc_bytes, stream);
    hipMemsetAsync(counts, 0, (size_t)n_total * sizeof(int), stream);
    hipMemsetAsync(d_out, 0, sizeof(float) * out_size, stream);

    // ---- CSR build ----
    const int eb = (n_edges + 255) / 256;
    hist_kernel<<<eb, 256, 0, stream>>>(edge_row, counts, n_edges);
    const int nscan = (n_total + SCAN_CHUNK - 1) / SCAN_CHUNK;  // 74
    scan_block_kernel<<<nscan, 256, 0, stream>>>(counts, offsets, bsums, n_total);
    scan_sums_kernel<<<1, 64, 0, stream>>>(bsums, nscan, offsets, n_total);
    scan_add_kernel<<<(n_total + 255) / 256, 256, 0, stream>>>(offsets, bsums, n_total);
    copy_kernel<<<(n_total + 1 + 255) / 256, 256, 0, stream>>>(offsets, cursor, n_total + 1);
    fill_kernel<<<eb, 256, 0, stream>>>(edge_row, edge_col, edge_val, cursor, pairs, n_edges);

    // ---- layer 0 ----
    concat_init_kernel<<<2048, 256, 0, stream>>>(user_emb, item_emb, buf0,
                                                 n_user_rows, n_total);
    const int ga_blocks = (batch * 16 + 255) / 256;
    gather_acc_kernel<<<ga_blocks, 256, 0, stream>>>(users, items, buf0,
                                                     u_acc, v_acc, batch, n_user_rows);

    // ---- 3 propagation layers (gather, no atomics, no memset) ----
    float* cur = buf0;
    float* nxt = buf1;
    const int rows_blocks = (n_total + 3) / 4;  // 4 waves/block, 1 wave/row
    for (int layer = 0; layer < 3; ++layer) {
        spmm_gather_kernel<<<rows_blocks, 256, 0, stream>>>(offsets, pairs, cur, nxt, n_total);
        gather_acc_kernel<<<ga_blocks, 256, 0, stream>>>(users, items, nxt,
                                                         u_acc, v_acc, batch, n_user_rows);
        float* tmp = cur; cur = nxt; nxt = tmp;
    }

    // ---- loss ----
    loss_kernel<<<(batch + 255) / 256, 256, 0, stream>>>(u_acc, v_acc, labels,
                                                         (float*)d_out, batch);
}